// Round 7
// baseline (562.705 us; speedup 1.0000x reference)
//
#include <hip/hip_runtime.h>

// Problem constants
#define BATCH 4
#define CH    64
#define HH    64
#define WW    64
#define LL    4096          // HH*WW
#define SPLITS 8
#define RPS   512           // LL/SPLITS
#define BM    128           // r tile
#define BN    128           // l tile
#define NRT   (RPS/BM)      // 4

// LDS tile: 13 slots of 16B per row (12 data = 3 comps x 32 k, 1 pad), 208 B/row
#define RSTB  208
#define BUFB  53248         // bytes per stage buffer
#define BSOFF 26624         // B side byte offset within buffer (1664*16)

// Padded pre-split global image Gp[side][b][comp][c8(8)][4356][8ch] (ushort)
#define PAD_L   4356        // 66*66
#define GP_BYTE_BASE 1376256
#define GP_SIDE_STRIDE 6690816   // 4*3*8*4356*8*2
#define GP_B_STRIDE    1672704   // 3*8*4356*8*2
#define GP_COMP_STRIDE 557568    // 8*4356*16
#define GP_TOTAL       13381632  // 2*GP_SIDE_STRIDE
#define HOFF           278784    // h half-channel addend: 4*PAD_L*16

// Workspace layout (float words)
#define WS_SSQ_RS 0
#define WS_SSQ_LR 16384
#define WS_INV_RS 32768
#define WS_INV_LR 49152
#define WS_PMAX   65536      // [B*SPLITS*L] = 131072
#define WS_PARG   196608     // [B*SPLITS*L] = 131072
#define WS_ARG    327680     // [B*L]

typedef __attribute__((ext_vector_type(8))) short short8b;
typedef __attribute__((ext_vector_type(4))) float f32x4;
typedef __attribute__((ext_vector_type(16))) float f32x16;

__device__ __forceinline__ void gload16(const void* g, void* l) {
    __builtin_amdgcn_global_load_lds(
        (const __attribute__((address_space(1))) unsigned int*)g,
        (__attribute__((address_space(3))) unsigned int*)l, 16, 0, 0);
}

// -------- 0) pre-split: fp32 -> 3 truncated bf16 comps, padded image --------
__global__ void k_split(const float* __restrict__ lrsr,
                        const float* __restrict__ refsr,
                        float* __restrict__ ws) {
    int tid  = threadIdx.x;
    int pos  = blockIdx.x * 256 + tid;          // 0..4095
    int c8   = blockIdx.y;                      // 0..7
    int side = blockIdx.z >> 2;                 // 0 = refsr(A), 1 = lrsr(B)
    int b    = blockIdx.z & 3;
    const float* src = (side ? lrsr : refsr) + (size_t)b * CH * LL + c8 * 8 * LL + pos;
    int ppos = (pos >> 6) * 66 + (pos & 63) + 67;   // (y+1)*66 + (x+1)
    char* dst = (char*)ws + GP_BYTE_BASE + side * GP_SIDE_STRIDE + b * GP_B_STRIDE
              + (size_t)(c8 * PAD_L + ppos) * 16;
    union { unsigned short u[8]; uint4 v; } w0, w1, w2;
    #pragma unroll
    for (int cc = 0; cc < 8; ++cc) {
        float x = src[cc * LL];
        unsigned u0 = __float_as_uint(x);
        float f0 = __uint_as_float(u0 & 0xffff0000u);
        float r1 = x - f0;
        unsigned u1 = __float_as_uint(r1);
        float f1 = __uint_as_float(u1 & 0xffff0000u);
        float r2 = r1 - f1;
        w0.u[cc] = (unsigned short)(u0 >> 16);
        w1.u[cc] = (unsigned short)(u1 >> 16);
        w2.u[cc] = (unsigned short)(__float_as_uint(r2) >> 16);
    }
    *(uint4*)(dst)                      = w0.v;
    *(uint4*)(dst + GP_COMP_STRIDE)     = w1.v;
    *(uint4*)(dst + 2 * GP_COMP_STRIDE) = w2.v;
}

// -------- 1) channel sum-of-squares per position (both inputs) --------
__global__ void k_ssq(const float* __restrict__ lrsr,
                      const float* __restrict__ refsr,
                      float* __restrict__ ws) {
    int t = blockIdx.x * 256 + threadIdx.x;      // 0..B*L-1
    int b = t >> 12;
    int r = t & (LL - 1);
    const float* pl = lrsr + (size_t)b * CH * LL + r;
    const float* pr = refsr + (size_t)b * CH * LL + r;
    float sl = 0.f, sr = 0.f;
    #pragma unroll 8
    for (int c = 0; c < CH; ++c) {
        float a = pl[c * LL]; sl += a * a;
        float d = pr[c * LL]; sr += d * d;
    }
    ws[WS_SSQ_RS + t] = sr;
    ws[WS_SSQ_LR + t] = sl;
}

// -------- 2) 3x3 box-sum of ssq (zero pad) -> 1/max(norm,eps) --------
__global__ void k_inv(float* __restrict__ ws) {
    int t = blockIdx.x * 256 + threadIdx.x;      // 0..B*L-1
    int b = t >> 12;
    int r = t & (LL - 1);
    int y = r >> 6, x = r & 63;
    float srs = 0.f, slr = 0.f;
    for (int di = -1; di <= 1; ++di) {
        int yy = y + di;
        if ((unsigned)yy >= (unsigned)HH) continue;
        for (int dj = -1; dj <= 1; ++dj) {
            int xx = x + dj;
            if ((unsigned)xx >= (unsigned)WW) continue;
            int idx = b * LL + yy * WW + xx;
            srs += ws[WS_SSQ_RS + idx];
            slr += ws[WS_SSQ_LR + idx];
        }
    }
    ws[WS_INV_RS + t] = 1.f / fmaxf(sqrtf(srs), 1e-12f);
    ws[WS_INV_LR + t] = 1.f / fmaxf(sqrtf(slr), 1e-12f);
}

// -------- 3) MFMA corr GEMM: 32x32x16, dbuf LDS, counted-vmcnt pipeline -----
__global__ __launch_bounds__(512, 1)
void k_corrmax(float* __restrict__ ws) {
    __shared__ __align__(16) char LDSB[2 * BUFB];   // 104 KB double buffer

    int tid  = threadIdx.x;
    int b    = blockIdx.z;
    int bx   = blockIdx.x;
    int l0   = bx * BN;
    int rbs  = blockIdx.y * RPS;

    int lane = tid & 63;
    int w    = tid >> 6;        // wave 0..7
    int wr   = w >> 2;          // r half 0..1 (64 rows each)
    int wc   = w & 3;           // l quarter 0..3 (32 cols each)
    int l31  = lane & 31;
    int g2   = lane >> 5;       // k-octet selector

    const float* invn_rs = ws + WS_INV_RS + b * LL;
    const char*  gpB = (const char*)ws + GP_BYTE_BASE + b * GP_B_STRIDE;

    // ---- per-lane staging constants: waves 0-3 issue 7 chunks, 4-7 issue 6 ----
    int LCb[7];
    int sideF[7];
    #pragma unroll
    for (int n = 0; n < 7; ++n) {
        int cid = n * 8 + w;
        if (cid < 52) {
            int G    = cid * 64 + lane;
            int side = (G >= 1664) ? 1 : 0;
            int gg   = G - side * 1664;
            int row  = gg / 13;
            int slot = gg - row * 13;
            int base = side * GP_SIDE_STRIDE + (row + 2 * (row >> 6)) * 16;
            if (slot < 12)
                base += (slot >> 2) * GP_COMP_STRIDE + (slot & 3) * (PAD_L * 16);
            LCb[n]   = base;
            sideF[n] = side;
        } else { LCb[n] = 0; sideF[n] = 0; }
    }

    // ---- fragment LDS byte offsets (ks adds +32, comp c at +c*64) ----
    int aoff[2][3], boff[3];
    #pragma unroll
    for (int mf = 0; mf < 2; ++mf)
        #pragma unroll
        for (int c = 0; c < 3; ++c)
            aoff[mf][c] = (wr * 64 + mf * 32 + l31) * RSTB + c * 64 + g2 * 16;
    #pragma unroll
    for (int c = 0; c < 3; ++c)
        boff[c] = BSOFF + (wc * 32 + l31) * RSTB + c * 64 + g2 * 16;

    int yb = rbs >> 6;          // A-side y base
    int yB = bx * 2;            // B-side y base

    auto issue = [&](int rt2, int q2, int h2, int bufo) {
        int i2 = (q2 < 3) ? -1 : ((q2 < 6) ? 0 : 1);
        int j2 = q2 - (i2 + 1) * 3 - 1;
        int suA = ((yb + rt2 * 2 + 1 + i2) * 66 + 1 + j2) * 16 + h2 * HOFF;
        int suB = ((yB + 1 + i2) * 66 + 1 + j2) * 16 + h2 * HOFF;
        #pragma unroll
        for (int n = 0; n < 7; ++n) {
            int cid = n * 8 + w;
            if (cid < 52) {        // wave-uniform condition
                int su = sideF[n] ? suB : suA;
                gload16(gpB + (LCb[n] + su), LDSB + bufo + cid * 1024);
            }
        }
    };

    float rm = -1e30f;          // running max for this lane's l column
    int   ra = 0;

    // ---- prologue: S0 -> buf0, S1 -> buf1 ----
    issue(0, 0, 0, 0);
    issue(0, 0, 1, BUFB);
    int irt = 0, iq = 1, ih = 0;   // next stage to issue = S2
    int isleft = NRT * 18 - 2;     // 70 stages remain to issue
    int cur = 0;

    for (int rt = 0; rt < NRT; ++rt) {
        int r0 = rbs + rt * BM;

        f32x16 acc[2];
        #pragma unroll
        for (int mf = 0; mf < 2; ++mf)
            #pragma unroll
            for (int e = 0; e < 16; ++e) acc[mf][e] = 0.f;

        for (int q = 0; q < 9; ++q) {
            for (int h = 0; h < 2; ++h) {
                // ---- wait for current stage's DMA (counted, never 0 mid-loop) ----
                if (rt == NRT - 1 && q == 8 && h == 1)
                    asm volatile("s_waitcnt vmcnt(0)" ::: "memory");
                else
                    asm volatile("s_waitcnt vmcnt(6)" ::: "memory");
                __builtin_amdgcn_s_barrier();
                __builtin_amdgcn_sched_barrier(0);

                // ---- fragments + MFMA from current buffer ----
                const char* lb = LDSB + cur * BUFB;
                #pragma unroll
                for (int ks = 0; ks < 2; ++ks) {
                    short8b a[2][3], bv[3];
                    #pragma unroll
                    for (int mf = 0; mf < 2; ++mf)
                        #pragma unroll
                        for (int c = 0; c < 3; ++c)
                            a[mf][c] = *(const short8b*)(lb + aoff[mf][c] + ks * 32);
                    #pragma unroll
                    for (int c = 0; c < 3; ++c)
                        bv[c] = *(const short8b*)(lb + boff[c] + ks * 32);
                    __builtin_amdgcn_s_setprio(1);
                    #pragma unroll
                    for (int mf = 0; mf < 2; ++mf) {
                        f32x16 d = acc[mf];
                        d = __builtin_amdgcn_mfma_f32_32x32x16_bf16(a[mf][0], bv[0], d, 0, 0, 0);
                        d = __builtin_amdgcn_mfma_f32_32x32x16_bf16(a[mf][0], bv[1], d, 0, 0, 0);
                        d = __builtin_amdgcn_mfma_f32_32x32x16_bf16(a[mf][1], bv[0], d, 0, 0, 0);
                        d = __builtin_amdgcn_mfma_f32_32x32x16_bf16(a[mf][1], bv[1], d, 0, 0, 0);
                        d = __builtin_amdgcn_mfma_f32_32x32x16_bf16(a[mf][0], bv[2], d, 0, 0, 0);
                        d = __builtin_amdgcn_mfma_f32_32x32x16_bf16(a[mf][2], bv[0], d, 0, 0, 0);
                        acc[mf] = d;
                    }
                    __builtin_amdgcn_s_setprio(0);
                }
                __builtin_amdgcn_sched_barrier(0);
                __builtin_amdgcn_s_barrier();      // all waves done reading buf[cur]

                // ---- issue stage s+2 into the buffer just freed ----
                if (isleft > 0) {
                    issue(irt, iq, ih, cur * BUFB);
                    ih ^= 1;
                    if (!ih) { ++iq; if (iq == 9) { iq = 0; ++irt; } }
                    --isleft;
                }
                cur ^= 1;
            }
        }

        // ---- epilogue: scale by invn_rs, merge into running (m,a) ----
        // C layout: col = lane&31, row = (reg&3) + 8*(reg>>2) + 4*(lane>>5)
        f32x4 inv4[2][4];
        #pragma unroll
        for (int mf = 0; mf < 2; ++mf)
            #pragma unroll
            for (int rb = 0; rb < 4; ++rb)
                inv4[mf][rb] = *(const f32x4*)&invn_rs[r0 + wr * 64 + mf * 32 + g2 * 4 + rb * 8];
        #pragma unroll
        for (int mf = 0; mf < 2; ++mf)
            #pragma unroll
            for (int reg = 0; reg < 16; ++reg) {
                int r = r0 + wr * 64 + mf * 32 + (reg & 3) + 8 * (reg >> 2) + 4 * g2;
                float val = acc[mf][reg] * inv4[mf][reg >> 2][reg & 3];
                if (val > rm || (val == rm && r < ra)) { rm = val; ra = r; }
            }
    }

    // ---- lane-pair merge (lanes l, l+32 hold same column) ----
    {
        float ov = __shfl_xor(rm, 32);
        int   oi = __shfl_xor(ra, 32);
        if (ov > rm || (ov == rm && oi < ra)) { rm = ov; ra = oi; }
    }
    // ---- cross-wave merge (DMA fully drained by final stage's vmcnt(0)) ----
    __syncthreads();
    float* sm2 = (float*)LDSB;          // [2][128]
    int*   si2 = (int*)LDSB + 256;      // [2][128]
    if (lane < 32) {
        sm2[wr * 128 + wc * 32 + l31] = rm;
        si2[wr * 128 + wc * 32 + l31] = ra;
    }
    __syncthreads();
    if (tid < 128) {
        float bm = sm2[tid]; int ba = si2[tid];
        float v  = sm2[128 + tid]; int a2 = si2[128 + tid];
        if (v > bm || (v == bm && a2 < ba)) { bm = v; ba = a2; }
        int l = l0 + tid;
        int o = (b * SPLITS + blockIdx.y) * LL + l;
        ws[WS_PMAX + o] = bm;
        ((int*)ws)[WS_PARG + o] = ba;
    }
}

// -------- 4) reduce over splits -> s output + final argmax --------
__global__ void k_reduce(float* __restrict__ ws, float* __restrict__ out) {
    int t = blockIdx.x * 256 + threadIdx.x;   // 0..B*L-1
    int b = t >> 12;
    int l = t & (LL - 1);
    float bm = -1e30f; int ba = 0;
    for (int s = 0; s < SPLITS; ++s) {        // splits are ascending r ranges
        int o = (b * SPLITS + s) * LL + l;
        float v = ws[WS_PMAX + o];
        int   a = ((int*)ws)[WS_PARG + o];
        if (v > bm || (v == bm && a < ba)) { bm = v; ba = a; }
    }
    out[t] = bm * ws[WS_INV_LR + t];          // s: [B,1,H,W] flat
    ((int*)ws)[WS_ARG + t] = ba;
}

// -------- 5) gather from ref via argmax + fold(3x3, pad 1) --------
__global__ void k_fold(const float* __restrict__ ref,
                       const float* __restrict__ ws,
                       float* __restrict__ out) {
    int t = blockIdx.x * 256 + threadIdx.x;   // 0..B*C*L-1
    int b = t >> 18;
    int c = (t >> 12) & 63;
    int yx = t & (LL - 1);
    int y = yx >> 6, x = yx & 63;
    const int* ab = ((const int*)ws) + WS_ARG + b * LL;
    const float* rb = ref + (size_t)b * CH * LL + c * LL;
    float s = 0.f;
    #pragma unroll
    for (int i = 0; i < 3; ++i) {
        int yp = y + 1 - i;
        if ((unsigned)yp >= (unsigned)HH) continue;
        #pragma unroll
        for (int j = 0; j < 3; ++j) {
            int xp = x + 1 - j;
            if ((unsigned)xp >= (unsigned)WW) continue;
            int r = ab[yp * WW + xp];
            int ry = (r >> 6) + i - 1;
            int rx = (r & 63) + j - 1;
            if ((unsigned)ry < (unsigned)HH && (unsigned)rx < (unsigned)WW)
                s += rb[ry * WW + rx];
        }
    }
    out[BATCH * LL + t] = s;                  // trans after s (16384 floats)
}

extern "C" void kernel_launch(void* const* d_in, const int* in_sizes, int n_in,
                              void* d_out, int out_size, void* d_ws, size_t ws_size,
                              hipStream_t stream) {
    const float* lrsr = (const float*)d_in[0];
    const float* refsr = (const float*)d_in[1];
    const float* ref  = (const float*)d_in[2];
    float* out = (float*)d_out;
    float* ws  = (float*)d_ws;

    // zero the padded pre-split region (borders must be 0)
    hipMemsetAsync((char*)d_ws + GP_BYTE_BASE, 0, GP_TOTAL, stream);
    k_split<<<dim3(16, 8, 8), dim3(256), 0, stream>>>(lrsr, refsr, ws);
    k_ssq<<<dim3(BATCH * LL / 256), dim3(256), 0, stream>>>(lrsr, refsr, ws);
    k_inv<<<dim3(BATCH * LL / 256), dim3(256), 0, stream>>>(ws);
    k_corrmax<<<dim3(LL / BN, SPLITS, BATCH), dim3(512), 0, stream>>>(ws);
    k_reduce<<<dim3(BATCH * LL / 256), dim3(256), 0, stream>>>(ws, out);
    k_fold<<<dim3(BATCH * CH * LL / 256), dim3(256), 0, stream>>>(ref, ws, out);
}

// Round 8
// 536.179 us; speedup vs baseline: 1.0495x; 1.0495x over previous
//
#include <hip/hip_runtime.h>

// Problem constants
#define BATCH 4
#define CH    64
#define HH    64
#define WW    64
#define LL    4096          // HH*WW
#define SPLITS 8
#define RPS   512           // LL/SPLITS
#define BM    128           // r tile
#define BN    128           // l tile
#define NRT   (RPS/BM)      // 4

// LDS tile: 13 slots of 16B per row (12 data = 3 comps x 32 k, 1 pad), 208 B/row
#define RSTB  208
#define BUFB  53248         // bytes per stage buffer (single buffer -> 2 blocks/CU)
#define BSOFF 26624         // B side byte offset within buffer (1664*16)

// Padded pre-split global image Gp[side][b][comp][c8(8)][4356][8ch] (ushort)
#define PAD_L   4356        // 66*66
#define GP_BYTE_BASE 1376256
#define GP_SIDE_STRIDE 6690816   // 4*3*8*4356*8*2
#define GP_B_STRIDE    1672704   // 3*8*4356*8*2
#define GP_COMP_STRIDE 557568    // 8*4356*16
#define GP_TOTAL       13381632  // 2*GP_SIDE_STRIDE
#define HOFF           278784    // h half-channel addend: 4*PAD_L*16

// Workspace layout (float words)
#define WS_SSQ_RS 0
#define WS_SSQ_LR 16384
#define WS_INV_RS 32768
#define WS_INV_LR 49152
#define WS_PMAX   65536      // [B*SPLITS*L] = 131072
#define WS_PARG   196608     // [B*SPLITS*L] = 131072
#define WS_ARG    327680     // [B*L]

typedef __attribute__((ext_vector_type(8))) short short8b;
typedef __attribute__((ext_vector_type(4))) float f32x4;
typedef __attribute__((ext_vector_type(16))) float f32x16;

__device__ __forceinline__ void gload16(const void* g, void* l) {
    __builtin_amdgcn_global_load_lds(
        (const __attribute__((address_space(1))) unsigned int*)g,
        (__attribute__((address_space(3))) unsigned int*)l, 16, 0, 0);
}

// -------- 0) pre-split: fp32 -> 3 truncated bf16 comps, padded image --------
__global__ void k_split(const float* __restrict__ lrsr,
                        const float* __restrict__ refsr,
                        float* __restrict__ ws) {
    int tid  = threadIdx.x;
    int pos  = blockIdx.x * 256 + tid;          // 0..4095
    int c8   = blockIdx.y;                      // 0..7
    int side = blockIdx.z >> 2;                 // 0 = refsr(A), 1 = lrsr(B)
    int b    = blockIdx.z & 3;
    const float* src = (side ? lrsr : refsr) + (size_t)b * CH * LL + c8 * 8 * LL + pos;
    int ppos = (pos >> 6) * 66 + (pos & 63) + 67;   // (y+1)*66 + (x+1)
    char* dst = (char*)ws + GP_BYTE_BASE + side * GP_SIDE_STRIDE + b * GP_B_STRIDE
              + (size_t)(c8 * PAD_L + ppos) * 16;
    union { unsigned short u[8]; uint4 v; } w0, w1, w2;
    #pragma unroll
    for (int cc = 0; cc < 8; ++cc) {
        float x = src[cc * LL];
        unsigned u0 = __float_as_uint(x);
        float f0 = __uint_as_float(u0 & 0xffff0000u);
        float r1 = x - f0;
        unsigned u1 = __float_as_uint(r1);
        float f1 = __uint_as_float(u1 & 0xffff0000u);
        float r2 = r1 - f1;
        w0.u[cc] = (unsigned short)(u0 >> 16);
        w1.u[cc] = (unsigned short)(u1 >> 16);
        w2.u[cc] = (unsigned short)(__float_as_uint(r2) >> 16);
    }
    *(uint4*)(dst)                      = w0.v;
    *(uint4*)(dst + GP_COMP_STRIDE)     = w1.v;
    *(uint4*)(dst + 2 * GP_COMP_STRIDE) = w2.v;
}

// -------- 1) channel sum-of-squares per position (both inputs) --------
__global__ void k_ssq(const float* __restrict__ lrsr,
                      const float* __restrict__ refsr,
                      float* __restrict__ ws) {
    int t = blockIdx.x * 256 + threadIdx.x;      // 0..B*L-1
    int b = t >> 12;
    int r = t & (LL - 1);
    const float* pl = lrsr + (size_t)b * CH * LL + r;
    const float* pr = refsr + (size_t)b * CH * LL + r;
    float sl = 0.f, sr = 0.f;
    #pragma unroll 8
    for (int c = 0; c < CH; ++c) {
        float a = pl[c * LL]; sl += a * a;
        float d = pr[c * LL]; sr += d * d;
    }
    ws[WS_SSQ_RS + t] = sr;
    ws[WS_SSQ_LR + t] = sl;
}

// -------- 2) 3x3 box-sum of ssq (zero pad) -> 1/max(norm,eps) --------
__global__ void k_inv(float* __restrict__ ws) {
    int t = blockIdx.x * 256 + threadIdx.x;      // 0..B*L-1
    int b = t >> 12;
    int r = t & (LL - 1);
    int y = r >> 6, x = r & 63;
    float srs = 0.f, slr = 0.f;
    for (int di = -1; di <= 1; ++di) {
        int yy = y + di;
        if ((unsigned)yy >= (unsigned)HH) continue;
        for (int dj = -1; dj <= 1; ++dj) {
            int xx = x + dj;
            if ((unsigned)xx >= (unsigned)WW) continue;
            int idx = b * LL + yy * WW + xx;
            srs += ws[WS_SSQ_RS + idx];
            slr += ws[WS_SSQ_LR + idx];
        }
    }
    ws[WS_INV_RS + t] = 1.f / fmaxf(sqrtf(srs), 1e-12f);
    ws[WS_INV_LR + t] = 1.f / fmaxf(sqrtf(slr), 1e-12f);
}

// -------- 3) MFMA corr GEMM: 32x32x16, single 52KB buffer, R4 schedule ------
// Per stage: read frags -> barrier -> issue next stage DMA -> MFMA -> barrier.
// 2 phase-shifted blocks/CU cover each other's DMA drains (m114 overlap).
__global__ __launch_bounds__(512, 2)
void k_corrmax(float* __restrict__ ws) {
    __shared__ __align__(16) char LDSB[BUFB];   // 52 KB single buffer

    int tid  = threadIdx.x;
    int b    = blockIdx.z;
    int bx   = blockIdx.x;
    int l0   = bx * BN;
    int rbs  = blockIdx.y * RPS;

    int lane = tid & 63;
    int w    = tid >> 6;        // wave 0..7
    int wr   = w >> 2;          // r half 0..1 (64 rows each)
    int wc   = w & 3;           // l quarter 0..3 (32 cols each)
    int l31  = lane & 31;
    int g2   = lane >> 5;       // k-octet selector

    const float* invn_rs = ws + WS_INV_RS + b * LL;
    const char*  gpB = (const char*)ws + GP_BYTE_BASE + b * GP_B_STRIDE;

    // ---- per-lane staging constants: waves 0-3 issue 7 chunks, 4-7 issue 6 ----
    int LCb[7];
    int sideF[7];
    #pragma unroll
    for (int n = 0; n < 7; ++n) {
        int cid = n * 8 + w;
        if (cid < 52) {
            int G    = cid * 64 + lane;
            int side = (G >= 1664) ? 1 : 0;
            int gg   = G - side * 1664;
            int row  = gg / 13;
            int slot = gg - row * 13;
            int base = side * GP_SIDE_STRIDE + (row + 2 * (row >> 6)) * 16;
            if (slot < 12)
                base += (slot >> 2) * GP_COMP_STRIDE + (slot & 3) * (PAD_L * 16);
            LCb[n]   = base;
            sideF[n] = side;
        } else { LCb[n] = 0; sideF[n] = 0; }
    }

    // ---- fragment LDS byte offsets (ks adds +32, comp c at +c*64) ----
    int aoff[2][3], boff[3];
    #pragma unroll
    for (int mf = 0; mf < 2; ++mf)
        #pragma unroll
        for (int c = 0; c < 3; ++c)
            aoff[mf][c] = (wr * 64 + mf * 32 + l31) * RSTB + c * 64 + g2 * 16;
    #pragma unroll
    for (int c = 0; c < 3; ++c)
        boff[c] = BSOFF + (wc * 32 + l31) * RSTB + c * 64 + g2 * 16;

    int yb = rbs >> 6;          // A-side y base
    int yB = bx * 2;            // B-side y base

    auto issue = [&](int rt2, int q2, int h2) {
        int i2 = (q2 < 3) ? -1 : ((q2 < 6) ? 0 : 1);
        int j2 = q2 - (i2 + 1) * 3 - 1;
        int suA = ((yb + rt2 * 2 + 1 + i2) * 66 + 1 + j2) * 16 + h2 * HOFF;
        int suB = ((yB + 1 + i2) * 66 + 1 + j2) * 16 + h2 * HOFF;
        #pragma unroll
        for (int n = 0; n < 7; ++n) {
            int cid = n * 8 + w;
            if (cid < 52) {        // wave-uniform condition
                int su = sideF[n] ? suB : suA;
                gload16(gpB + (LCb[n] + su), LDSB + cid * 1024);
            }
        }
    };

    float rm = -1e30f;          // running max for this lane's l column
    int   ra = 0;

    issue(0, 0, 0);
    __syncthreads();            // S0 landed (vmcnt(0) before barrier)

    for (int rt = 0; rt < NRT; ++rt) {
        int r0 = rbs + rt * BM;

        f32x16 acc[2];
        #pragma unroll
        for (int mf = 0; mf < 2; ++mf)
            #pragma unroll
            for (int e = 0; e < 16; ++e) acc[mf][e] = 0.f;

        for (int q = 0; q < 9; ++q) {
            for (int h = 0; h < 2; ++h) {
                // ---- read fragments of current stage into registers ----
                short8b a[2][2][3], bv[2][3];
                #pragma unroll
                for (int ks = 0; ks < 2; ++ks) {
                    #pragma unroll
                    for (int mf = 0; mf < 2; ++mf)
                        #pragma unroll
                        for (int c = 0; c < 3; ++c)
                            a[ks][mf][c] = *(const short8b*)(LDSB + aoff[mf][c] + ks * 32);
                    #pragma unroll
                    for (int c = 0; c < 3; ++c)
                        bv[ks][c] = *(const short8b*)(LDSB + boff[c] + ks * 32);
                }
                __syncthreads();   // all waves read buf; safe to overwrite

                // ---- issue next stage's DMA into the same buffer ----
                if (!(rt == NRT - 1 && q == 8 && h == 1)) {
                    int h2 = h ^ 1, q2 = q, rt2 = rt;
                    if (h == 1) { q2 = q + 1; h2 = 0; if (q2 == 9) { q2 = 0; rt2 = (rt + 1) & (NRT - 1); } }
                    issue(rt2, q2, h2);
                }

                // ---- 6-product MFMA (register-only; DMA flies underneath) ----
                __builtin_amdgcn_s_setprio(1);
                #pragma unroll
                for (int ks = 0; ks < 2; ++ks)
                    #pragma unroll
                    for (int mf = 0; mf < 2; ++mf) {
                        f32x16 d = acc[mf];
                        d = __builtin_amdgcn_mfma_f32_32x32x16_bf16(a[ks][mf][0], bv[ks][0], d, 0, 0, 0);
                        d = __builtin_amdgcn_mfma_f32_32x32x16_bf16(a[ks][mf][0], bv[ks][1], d, 0, 0, 0);
                        d = __builtin_amdgcn_mfma_f32_32x32x16_bf16(a[ks][mf][1], bv[ks][0], d, 0, 0, 0);
                        d = __builtin_amdgcn_mfma_f32_32x32x16_bf16(a[ks][mf][1], bv[ks][1], d, 0, 0, 0);
                        d = __builtin_amdgcn_mfma_f32_32x32x16_bf16(a[ks][mf][0], bv[ks][2], d, 0, 0, 0);
                        d = __builtin_amdgcn_mfma_f32_32x32x16_bf16(a[ks][mf][2], bv[ks][0], d, 0, 0, 0);
                        acc[mf] = d;
                    }
                __builtin_amdgcn_s_setprio(0);
                __syncthreads();   // vmcnt(0): next stage landed
            }
        }

        // ---- epilogue: scale by invn_rs, merge into running (m,a) ----
        // C layout: col = lane&31, row = (reg&3) + 8*(reg>>2) + 4*(lane>>5)
        f32x4 inv4[2][4];
        #pragma unroll
        for (int mf = 0; mf < 2; ++mf)
            #pragma unroll
            for (int rb = 0; rb < 4; ++rb)
                inv4[mf][rb] = *(const f32x4*)&invn_rs[r0 + wr * 64 + mf * 32 + g2 * 4 + rb * 8];
        #pragma unroll
        for (int mf = 0; mf < 2; ++mf)
            #pragma unroll
            for (int reg = 0; reg < 16; ++reg) {
                int r = r0 + wr * 64 + mf * 32 + (reg & 3) + 8 * (reg >> 2) + 4 * g2;
                float val = acc[mf][reg] * inv4[mf][reg >> 2][reg & 3];
                if (val > rm || (val == rm && r < ra)) { rm = val; ra = r; }
            }
    }

    // ---- lane-pair merge (lanes l, l+32 hold same column) ----
    {
        float ov = __shfl_xor(rm, 32);
        int   oi = __shfl_xor(ra, 32);
        if (ov > rm || (ov == rm && oi < ra)) { rm = ov; ra = oi; }
    }
    // ---- cross-wave merge (DMA quiescent after final stage's drain) ----
    __syncthreads();
    float* sm2 = (float*)LDSB;          // [2][128]
    int*   si2 = (int*)LDSB + 256;      // [2][128]
    if (lane < 32) {
        sm2[wr * 128 + wc * 32 + l31] = rm;
        si2[wr * 128 + wc * 32 + l31] = ra;
    }
    __syncthreads();
    if (tid < 128) {
        float bm = sm2[tid]; int ba = si2[tid];
        float v  = sm2[128 + tid]; int a2 = si2[128 + tid];
        if (v > bm || (v == bm && a2 < ba)) { bm = v; ba = a2; }
        int l = l0 + tid;
        int o = (b * SPLITS + blockIdx.y) * LL + l;
        ws[WS_PMAX + o] = bm;
        ((int*)ws)[WS_PARG + o] = ba;
    }
}

// -------- 4) reduce over splits -> s output + final argmax --------
__global__ void k_reduce(float* __restrict__ ws, float* __restrict__ out) {
    int t = blockIdx.x * 256 + threadIdx.x;   // 0..B*L-1
    int b = t >> 12;
    int l = t & (LL - 1);
    float bm = -1e30f; int ba = 0;
    for (int s = 0; s < SPLITS; ++s) {        // splits are ascending r ranges
        int o = (b * SPLITS + s) * LL + l;
        float v = ws[WS_PMAX + o];
        int   a = ((int*)ws)[WS_PARG + o];
        if (v > bm || (v == bm && a < ba)) { bm = v; ba = a; }
    }
    out[t] = bm * ws[WS_INV_LR + t];          // s: [B,1,H,W] flat
    ((int*)ws)[WS_ARG + t] = ba;
}

// -------- 5) gather from ref via argmax + fold(3x3, pad 1) --------
__global__ void k_fold(const float* __restrict__ ref,
                       const float* __restrict__ ws,
                       float* __restrict__ out) {
    int t = blockIdx.x * 256 + threadIdx.x;   // 0..B*C*L-1
    int b = t >> 18;
    int c = (t >> 12) & 63;
    int yx = t & (LL - 1);
    int y = yx >> 6, x = yx & 63;
    const int* ab = ((const int*)ws) + WS_ARG + b * LL;
    const float* rb = ref + (size_t)b * CH * LL + c * LL;
    float s = 0.f;
    #pragma unroll
    for (int i = 0; i < 3; ++i) {
        int yp = y + 1 - i;
        if ((unsigned)yp >= (unsigned)HH) continue;
        #pragma unroll
        for (int j = 0; j < 3; ++j) {
            int xp = x + 1 - j;
            if ((unsigned)xp >= (unsigned)WW) continue;
            int r = ab[yp * WW + xp];
            int ry = (r >> 6) + i - 1;
            int rx = (r & 63) + j - 1;
            if ((unsigned)ry < (unsigned)HH && (unsigned)rx < (unsigned)WW)
                s += rb[ry * WW + rx];
        }
    }
    out[BATCH * LL + t] = s;                  // trans after s (16384 floats)
}

extern "C" void kernel_launch(void* const* d_in, const int* in_sizes, int n_in,
                              void* d_out, int out_size, void* d_ws, size_t ws_size,
                              hipStream_t stream) {
    const float* lrsr = (const float*)d_in[0];
    const float* refsr = (const float*)d_in[1];
    const float* ref  = (const float*)d_in[2];
    float* out = (float*)d_out;
    float* ws  = (float*)d_ws;

    // zero the padded pre-split region (borders must be 0)
    hipMemsetAsync((char*)d_ws + GP_BYTE_BASE, 0, GP_TOTAL, stream);
    k_split<<<dim3(16, 8, 8), dim3(256), 0, stream>>>(lrsr, refsr, ws);
    k_ssq<<<dim3(BATCH * LL / 256), dim3(256), 0, stream>>>(lrsr, refsr, ws);
    k_inv<<<dim3(BATCH * LL / 256), dim3(256), 0, stream>>>(ws);
    k_corrmax<<<dim3(LL / BN, SPLITS, BATCH), dim3(512), 0, stream>>>(ws);
    k_reduce<<<dim3(BATCH * LL / 256), dim3(256), 0, stream>>>(ws, out);
    k_fold<<<dim3(BATCH * CH * LL / 256), dim3(256), 0, stream>>>(ref, ws, out);
}

// Round 9
// 465.173 us; speedup vs baseline: 1.2097x; 1.1526x over previous
//
#include <hip/hip_runtime.h>

// Problem constants
#define BATCH 4
#define CH    64
#define HH    64
#define WW    64
#define LL    4096          // HH*WW
#define SPLITS 8
#define RPS   512           // LL/SPLITS
#define BM    128           // r tile
#define BN    128           // l tile
#define NRT   (RPS/BM)      // 4

// LDS: BK=16 ministage buffer: 256 rows x 96 B (3 comps x 16 k bf16), dbuf
#define RSTB  96
#define BUFB  24576         // bytes per stage buffer
#define BSOFF 12288         // B-side byte offset within buffer
#define CSTRIDE 139392      // ministage c8-pair stride: 2*PAD_L*16

// Padded pre-split global image Gp[side][b][comp][c8(8)][4356][8ch] (ushort)
#define PAD_L   4356        // 66*66
#define GP_BYTE_BASE 1376256
#define GP_SIDE_STRIDE 6690816   // 4*3*8*4356*8*2
#define GP_B_STRIDE    1672704   // 3*8*4356*8*2
#define GP_COMP_STRIDE 557568    // 8*4356*16
#define GP_TOTAL       13381632  // 2*GP_SIDE_STRIDE

// Workspace layout (float words)
#define WS_SSQ_RS 0
#define WS_SSQ_LR 16384
#define WS_INV_RS 32768
#define WS_INV_LR 49152
#define WS_PMAX   65536      // [B*SPLITS*L] = 131072
#define WS_PARG   196608     // [B*SPLITS*L] = 131072
#define WS_ARG    327680     // [B*L]

typedef __attribute__((ext_vector_type(8))) short short8b;
typedef __attribute__((ext_vector_type(4))) float f32x4;
typedef __attribute__((ext_vector_type(16))) float f32x16;

__device__ __forceinline__ void gload16(const void* g, void* l) {
    __builtin_amdgcn_global_load_lds(
        (const __attribute__((address_space(1))) unsigned int*)g,
        (__attribute__((address_space(3))) unsigned int*)l, 16, 0, 0);
}

// -------- 0) pre-split: fp32 -> 3 truncated bf16 comps, padded image --------
__global__ void k_split(const float* __restrict__ lrsr,
                        const float* __restrict__ refsr,
                        float* __restrict__ ws) {
    int tid  = threadIdx.x;
    int pos  = blockIdx.x * 256 + tid;          // 0..4095
    int c8   = blockIdx.y;                      // 0..7
    int side = blockIdx.z >> 2;                 // 0 = refsr(A), 1 = lrsr(B)
    int b    = blockIdx.z & 3;
    const float* src = (side ? lrsr : refsr) + (size_t)b * CH * LL + c8 * 8 * LL + pos;
    int ppos = (pos >> 6) * 66 + (pos & 63) + 67;   // (y+1)*66 + (x+1)
    char* dst = (char*)ws + GP_BYTE_BASE + side * GP_SIDE_STRIDE + b * GP_B_STRIDE
              + (size_t)(c8 * PAD_L + ppos) * 16;
    union { unsigned short u[8]; uint4 v; } w0, w1, w2;
    #pragma unroll
    for (int cc = 0; cc < 8; ++cc) {
        float x = src[cc * LL];
        unsigned u0 = __float_as_uint(x);
        float f0 = __uint_as_float(u0 & 0xffff0000u);
        float r1 = x - f0;
        unsigned u1 = __float_as_uint(r1);
        float f1 = __uint_as_float(u1 & 0xffff0000u);
        float r2 = r1 - f1;
        w0.u[cc] = (unsigned short)(u0 >> 16);
        w1.u[cc] = (unsigned short)(u1 >> 16);
        w2.u[cc] = (unsigned short)(__float_as_uint(r2) >> 16);
    }
    *(uint4*)(dst)                      = w0.v;
    *(uint4*)(dst + GP_COMP_STRIDE)     = w1.v;
    *(uint4*)(dst + 2 * GP_COMP_STRIDE) = w2.v;
}

// -------- 1) channel sum-of-squares per position (both inputs) --------
__global__ void k_ssq(const float* __restrict__ lrsr,
                      const float* __restrict__ refsr,
                      float* __restrict__ ws) {
    int t = blockIdx.x * 256 + threadIdx.x;      // 0..B*L-1
    int b = t >> 12;
    int r = t & (LL - 1);
    const float* pl = lrsr + (size_t)b * CH * LL + r;
    const float* pr = refsr + (size_t)b * CH * LL + r;
    float sl = 0.f, sr = 0.f;
    #pragma unroll 8
    for (int c = 0; c < CH; ++c) {
        float a = pl[c * LL]; sl += a * a;
        float d = pr[c * LL]; sr += d * d;
    }
    ws[WS_SSQ_RS + t] = sr;
    ws[WS_SSQ_LR + t] = sl;
}

// -------- 2) 3x3 box-sum of ssq (zero pad) -> 1/max(norm,eps) --------
__global__ void k_inv(float* __restrict__ ws) {
    int t = blockIdx.x * 256 + threadIdx.x;      // 0..B*L-1
    int b = t >> 12;
    int r = t & (LL - 1);
    int y = r >> 6, x = r & 63;
    float srs = 0.f, slr = 0.f;
    for (int di = -1; di <= 1; ++di) {
        int yy = y + di;
        if ((unsigned)yy >= (unsigned)HH) continue;
        for (int dj = -1; dj <= 1; ++dj) {
            int xx = x + dj;
            if ((unsigned)xx >= (unsigned)WW) continue;
            int idx = b * LL + yy * WW + xx;
            srs += ws[WS_SSQ_RS + idx];
            slr += ws[WS_SSQ_LR + idx];
        }
    }
    ws[WS_INV_RS + t] = 1.f / fmaxf(sqrtf(srs), 1e-12f);
    ws[WS_INV_LR + t] = 1.f / fmaxf(sqrtf(slr), 1e-12f);
}

// -------- 3) MFMA corr GEMM: 32x32x16, BK=16 dbuf, 1 barrier/ministage ------
// 256-thread blocks (proven 2-3 co-resident/CU); 4 waves, each owns 64x64.
__global__ __launch_bounds__(256, 3)
void k_corrmax(float* __restrict__ ws) {
    __shared__ __align__(16) char LDSB[2 * BUFB];   // 48 KB double buffer

    int tid  = threadIdx.x;
    int b    = blockIdx.z;
    int bx   = blockIdx.x;
    int l0   = bx * BN;
    int rbs  = blockIdx.y * RPS;

    int lane = tid & 63;
    int w    = tid >> 6;        // wave 0..3
    int wr   = w >> 1;          // r half 0..1 (64 rows)
    int wc   = w & 1;           // l half 0..1 (64 cols)
    int l31  = lane & 31;
    int g2   = lane >> 5;       // k-octet selector

    const float* invn_rs = ws + WS_INV_RS + b * LL;
    const char*  gpB = (const char*)ws + GP_BYTE_BASE + b * GP_B_STRIDE;
    int sB = w & 1;             // this wave stages side B?
    const char* bp = gpB + sB * GP_SIDE_STRIDE;

    // ---- per-lane staging constants: 6 chunk-issues per wave ----
    // chunk cid = n*4 + w; side = cid&1 = w&1; gg = (cid>>1)*64 + lane
    int LCb[6];
    #pragma unroll
    for (int n = 0; n < 6; ++n) {
        int gg   = (n * 2 + (w >> 1)) * 64 + lane;   // granule within side
        int row  = gg / 6;
        int slot = gg - row * 6;
        int comp = slot >> 1;
        int oct  = slot & 1;
        LCb[n] = comp * GP_COMP_STRIDE + oct * (PAD_L * 16)
               + (row + 2 * (row >> 6)) * 16;
    }
    int ldsw = sB * BSOFF + (w >> 1) * 1024;         // wave-uniform LDS chunk base

    // ---- fragment LDS byte bases (mf/nf add +3072, comp c adds +c*32) ----
    int abase = (wr * 64 + l31) * RSTB + g2 * 16;
    int bbase = BSOFF + (wc * 64 + l31) * RSTB + g2 * 16;

    int yb = rbs >> 6;          // A-side y base
    int yB = bx * 2;            // B-side y base

    // issue ministage (rt2,q2,m2): 6 async chunk loads into buffer bufo
    auto issue = [&](int rt2, int q2, int m2, int bufo) {
        int i2 = (q2 < 3) ? -1 : ((q2 < 6) ? 0 : 1);
        int j2 = q2 - (i2 + 1) * 3 - 1;
        int suA = ((yb + rt2 * 2 + 1 + i2) * 66 + 1 + j2) * 16 + m2 * CSTRIDE;
        int suB = ((yB + 1 + i2) * 66 + 1 + j2) * 16 + m2 * CSTRIDE;
        int su  = sB ? suB : suA;                    // wave-uniform select
        #pragma unroll
        for (int n = 0; n < 6; ++n)
            gload16(bp + (LCb[n] + su), LDSB + bufo + ldsw + n * 2048);
    };

    float rm[2] = {-1e30f, -1e30f};   // running max per nf column
    int   ra[2] = {0, 0};

    issue(0, 0, 0, 0);
    __syncthreads();            // S0 landed

    int cur = 0;
    for (int rt = 0; rt < NRT; ++rt) {
        int r0 = rbs + rt * BM;

        f32x16 acc[2][2];
        #pragma unroll
        for (int mf = 0; mf < 2; ++mf)
            #pragma unroll
            for (int nf = 0; nf < 2; ++nf)
                #pragma unroll
                for (int e = 0; e < 16; ++e) acc[mf][nf][e] = 0.f;

        for (int q = 0; q < 9; ++q) {
            #pragma unroll
            for (int m = 0; m < 4; ++m) {
                // ---- issue next ministage into the other buffer ----
                if (!(rt == NRT - 1 && q == 8 && m == 3)) {
                    int m2 = m + 1, q2 = q, rt2 = rt;
                    if (m2 == 4) { m2 = 0; ++q2; if (q2 == 9) { q2 = 0; ++rt2; } }
                    issue(rt2, q2, m2, (cur ^ 1) * BUFB);
                }
                // ---- fragments + MFMA from current buffer ----
                const char* lb = LDSB + cur * BUFB;
                short8b a[2][3], bv[2][3];
                #pragma unroll
                for (int mf = 0; mf < 2; ++mf)
                    #pragma unroll
                    for (int c = 0; c < 3; ++c)
                        a[mf][c] = *(const short8b*)(lb + abase + mf * 3072 + c * 32);
                #pragma unroll
                for (int nf = 0; nf < 2; ++nf)
                    #pragma unroll
                    for (int c = 0; c < 3; ++c)
                        bv[nf][c] = *(const short8b*)(lb + bbase + nf * 3072 + c * 32);
                __builtin_amdgcn_s_setprio(1);
                #pragma unroll
                for (int mf = 0; mf < 2; ++mf)
                    #pragma unroll
                    for (int nf = 0; nf < 2; ++nf) {
                        f32x16 d = acc[mf][nf];
                        d = __builtin_amdgcn_mfma_f32_32x32x16_bf16(a[mf][0], bv[nf][0], d, 0, 0, 0);
                        d = __builtin_amdgcn_mfma_f32_32x32x16_bf16(a[mf][0], bv[nf][1], d, 0, 0, 0);
                        d = __builtin_amdgcn_mfma_f32_32x32x16_bf16(a[mf][1], bv[nf][0], d, 0, 0, 0);
                        d = __builtin_amdgcn_mfma_f32_32x32x16_bf16(a[mf][1], bv[nf][1], d, 0, 0, 0);
                        d = __builtin_amdgcn_mfma_f32_32x32x16_bf16(a[mf][0], bv[nf][2], d, 0, 0, 0);
                        d = __builtin_amdgcn_mfma_f32_32x32x16_bf16(a[mf][2], bv[nf][0], d, 0, 0, 0);
                        acc[mf][nf] = d;
                    }
                __builtin_amdgcn_s_setprio(0);
                __syncthreads();   // next ministage landed; buf[cur] free
                cur ^= 1;
            }
        }

        // ---- epilogue: scale by invn_rs, merge into running (m,a) ----
        // C layout: col = lane&31, row = (reg&3) + 8*(reg>>2) + 4*(lane>>5)
        f32x4 inv4[2][4];
        #pragma unroll
        for (int mf = 0; mf < 2; ++mf)
            #pragma unroll
            for (int rb = 0; rb < 4; ++rb)
                inv4[mf][rb] = *(const f32x4*)&invn_rs[r0 + wr * 64 + mf * 32 + g2 * 4 + rb * 8];
        #pragma unroll
        for (int nf = 0; nf < 2; ++nf)
            #pragma unroll
            for (int mf = 0; mf < 2; ++mf)
                #pragma unroll
                for (int reg = 0; reg < 16; ++reg) {
                    int r = r0 + wr * 64 + mf * 32 + (reg & 3) + 8 * (reg >> 2) + 4 * g2;
                    float val = acc[mf][nf][reg] * inv4[mf][reg >> 2][reg & 3];
                    if (val > rm[nf] || (val == rm[nf] && r < ra[nf])) { rm[nf] = val; ra[nf] = r; }
                }
    }

    // ---- lane-pair merge (lanes l, l+32 hold same column) ----
    #pragma unroll
    for (int nf = 0; nf < 2; ++nf) {
        float ov = __shfl_xor(rm[nf], 32);
        int   oi = __shfl_xor(ra[nf], 32);
        if (ov > rm[nf] || (ov == rm[nf] && oi < ra[nf])) { rm[nf] = ov; ra[nf] = oi; }
    }
    // ---- cross-wave merge over wr halves (DMA quiescent) ----
    __syncthreads();
    float* sm2 = (float*)LDSB;          // [2][128]
    int*   si2 = (int*)LDSB + 256;      // [2][128]
    if (lane < 32) {
        #pragma unroll
        for (int nf = 0; nf < 2; ++nf) {
            sm2[wr * 128 + wc * 64 + nf * 32 + l31] = rm[nf];
            si2[wr * 128 + wc * 64 + nf * 32 + l31] = ra[nf];
        }
    }
    __syncthreads();
    if (tid < 128) {
        float bm = sm2[tid]; int ba = si2[tid];
        float v  = sm2[128 + tid]; int a2 = si2[128 + tid];
        if (v > bm || (v == bm && a2 < ba)) { bm = v; ba = a2; }
        int l = l0 + tid;
        int o = (b * SPLITS + blockIdx.y) * LL + l;
        ws[WS_PMAX + o] = bm;
        ((int*)ws)[WS_PARG + o] = ba;
    }
}

// -------- 4) reduce over splits -> s output + final argmax --------
__global__ void k_reduce(float* __restrict__ ws, float* __restrict__ out) {
    int t = blockIdx.x * 256 + threadIdx.x;   // 0..B*L-1
    int b = t >> 12;
    int l = t & (LL - 1);
    float bm = -1e30f; int ba = 0;
    for (int s = 0; s < SPLITS; ++s) {        // splits are ascending r ranges
        int o = (b * SPLITS + s) * LL + l;
        float v = ws[WS_PMAX + o];
        int   a = ((int*)ws)[WS_PARG + o];
        if (v > bm || (v == bm && a < ba)) { bm = v; ba = a; }
    }
    out[t] = bm * ws[WS_INV_LR + t];          // s: [B,1,H,W] flat
    ((int*)ws)[WS_ARG + t] = ba;
}

// -------- 5) gather from ref via argmax + fold(3x3, pad 1) --------
__global__ void k_fold(const float* __restrict__ ref,
                       const float* __restrict__ ws,
                       float* __restrict__ out) {
    int t = blockIdx.x * 256 + threadIdx.x;   // 0..B*C*L-1
    int b = t >> 18;
    int c = (t >> 12) & 63;
    int yx = t & (LL - 1);
    int y = yx >> 6, x = yx & 63;
    const int* ab = ((const int*)ws) + WS_ARG + b * LL;
    const float* rb = ref + (size_t)b * CH * LL + c * LL;
    float s = 0.f;
    #pragma unroll
    for (int i = 0; i < 3; ++i) {
        int yp = y + 1 - i;
        if ((unsigned)yp >= (unsigned)HH) continue;
        #pragma unroll
        for (int j = 0; j < 3; ++j) {
            int xp = x + 1 - j;
            if ((unsigned)xp >= (unsigned)WW) continue;
            int r = ab[yp * WW + xp];
            int ry = (r >> 6) + i - 1;
            int rx = (r & 63) + j - 1;
            if ((unsigned)ry < (unsigned)HH && (unsigned)rx < (unsigned)WW)
                s += rb[ry * WW + rx];
        }
    }
    out[BATCH * LL + t] = s;                  // trans after s (16384 floats)
}

extern "C" void kernel_launch(void* const* d_in, const int* in_sizes, int n_in,
                              void* d_out, int out_size, void* d_ws, size_t ws_size,
                              hipStream_t stream) {
    const float* lrsr = (const float*)d_in[0];
    const float* refsr = (const float*)d_in[1];
    const float* ref  = (const float*)d_in[2];
    float* out = (float*)d_out;
    float* ws  = (float*)d_ws;

    // zero the padded pre-split region (borders must be 0)
    hipMemsetAsync((char*)d_ws + GP_BYTE_BASE, 0, GP_TOTAL, stream);
    k_split<<<dim3(16, 8, 8), dim3(256), 0, stream>>>(lrsr, refsr, ws);
    k_ssq<<<dim3(BATCH * LL / 256), dim3(256), 0, stream>>>(lrsr, refsr, ws);
    k_inv<<<dim3(BATCH * LL / 256), dim3(256), 0, stream>>>(ws);
    k_corrmax<<<dim3(LL / BN, SPLITS, BATCH), dim3(256), 0, stream>>>(ws);
    k_reduce<<<dim3(BATCH * LL / 256), dim3(256), 0, stream>>>(ws, out);
    k_fold<<<dim3(BATCH * CH * LL / 256), dim3(256), 0, stream>>>(ref, ws, out);
}

// Round 10
// 404.504 us; speedup vs baseline: 1.3911x; 1.1500x over previous
//
#include <hip/hip_runtime.h>

// Problem constants
#define BATCH 4
#define CH    64
#define HH    64
#define WW    64
#define LL    4096          // HH*WW
#define SPLITS 4
#define RPS   1024          // LL/SPLITS
#define NRT   4             // r-tiles of 256 per block

// LDS K-tile buffer: per side 256 rows x 112 B (7 granules: 6 data + 1 dummy)
#define RSTB  112
#define BUFB  57344         // bytes per stage buffer (A 28KB | B 28KB)
#define BSOFF 28672         // B side byte offset within buffer
#define CSTRIDE 139392      // 16-ch group stride: 2*PAD_L*16

// Padded pre-split global image Gp[side][b][comp][c8(8)][4356][8ch] (ushort)
#define PAD_L   4356        // 66*66
#define GP_BYTE_BASE 1048576
#define GP_SIDE_STRIDE 6690816   // 4*3*8*4356*8*2
#define GP_B_STRIDE    1672704   // 3*8*4356*8*2
#define GP_COMP_STRIDE 557568    // 8*4356*16
#define GP_TOTAL       13381632  // 2*GP_SIDE_STRIDE

// Workspace layout (float words)
#define WS_SSQ_RS 0
#define WS_SSQ_LR 16384
#define WS_INV_RS 32768
#define WS_INV_LR 49152
#define WS_PMAX   65536      // [B*SPLITS*L] = 65536
#define WS_PARG   131072     // [B*SPLITS*L] = 65536
#define WS_ARG    196608     // [B*L]

typedef __attribute__((ext_vector_type(8))) short short8b;
typedef __attribute__((ext_vector_type(4))) float f32x4;
typedef __attribute__((ext_vector_type(16))) float f32x16;

__device__ __forceinline__ void gload16(const void* g, void* l) {
    __builtin_amdgcn_global_load_lds(
        (const __attribute__((address_space(1))) unsigned int*)g,
        (__attribute__((address_space(3))) unsigned int*)l, 16, 0, 0);
}

// -------- 0) pre-split: fp32 -> 3 truncated bf16 comps, padded image --------
__global__ void k_split(const float* __restrict__ lrsr,
                        const float* __restrict__ refsr,
                        float* __restrict__ ws) {
    int tid  = threadIdx.x;
    int pos  = blockIdx.x * 256 + tid;          // 0..4095
    int c8   = blockIdx.y;                      // 0..7
    int side = blockIdx.z >> 2;                 // 0 = refsr(A), 1 = lrsr(B)
    int b    = blockIdx.z & 3;
    const float* src = (side ? lrsr : refsr) + (size_t)b * CH * LL + c8 * 8 * LL + pos;
    int ppos = (pos >> 6) * 66 + (pos & 63) + 67;   // (y+1)*66 + (x+1)
    char* dst = (char*)ws + GP_BYTE_BASE + side * GP_SIDE_STRIDE + b * GP_B_STRIDE
              + (size_t)(c8 * PAD_L + ppos) * 16;
    union { unsigned short u[8]; uint4 v; } w0, w1, w2;
    #pragma unroll
    for (int cc = 0; cc < 8; ++cc) {
        float x = src[cc * LL];
        unsigned u0 = __float_as_uint(x);
        float f0 = __uint_as_float(u0 & 0xffff0000u);
        float r1 = x - f0;
        unsigned u1 = __float_as_uint(r1);
        float f1 = __uint_as_float(u1 & 0xffff0000u);
        float r2 = r1 - f1;
        w0.u[cc] = (unsigned short)(u0 >> 16);
        w1.u[cc] = (unsigned short)(u1 >> 16);
        w2.u[cc] = (unsigned short)(__float_as_uint(r2) >> 16);
    }
    *(uint4*)(dst)                      = w0.v;
    *(uint4*)(dst + GP_COMP_STRIDE)     = w1.v;
    *(uint4*)(dst + 2 * GP_COMP_STRIDE) = w2.v;
}

// -------- 1) channel sum-of-squares per position (both inputs) --------
__global__ void k_ssq(const float* __restrict__ lrsr,
                      const float* __restrict__ refsr,
                      float* __restrict__ ws) {
    int t = blockIdx.x * 256 + threadIdx.x;      // 0..B*L-1
    int b = t >> 12;
    int r = t & (LL - 1);
    const float* pl = lrsr + (size_t)b * CH * LL + r;
    const float* pr = refsr + (size_t)b * CH * LL + r;
    float sl = 0.f, sr = 0.f;
    #pragma unroll 8
    for (int c = 0; c < CH; ++c) {
        float a = pl[c * LL]; sl += a * a;
        float d = pr[c * LL]; sr += d * d;
    }
    ws[WS_SSQ_RS + t] = sr;
    ws[WS_SSQ_LR + t] = sl;
}

// -------- 2) 3x3 box-sum of ssq (zero pad) -> 1/max(norm,eps) --------
__global__ void k_inv(float* __restrict__ ws) {
    int t = blockIdx.x * 256 + threadIdx.x;      // 0..B*L-1
    int b = t >> 12;
    int r = t & (LL - 1);
    int y = r >> 6, x = r & 63;
    float srs = 0.f, slr = 0.f;
    for (int di = -1; di <= 1; ++di) {
        int yy = y + di;
        if ((unsigned)yy >= (unsigned)HH) continue;
        for (int dj = -1; dj <= 1; ++dj) {
            int xx = x + dj;
            if ((unsigned)xx >= (unsigned)WW) continue;
            int idx = b * LL + yy * WW + xx;
            srs += ws[WS_SSQ_RS + idx];
            slr += ws[WS_SSQ_LR + idx];
        }
    }
    ws[WS_INV_RS + t] = 1.f / fmaxf(sqrtf(srs), 1e-12f);
    ws[WS_INV_LR + t] = 1.f / fmaxf(sqrtf(slr), 1e-12f);
}

// -------- 3) MFMA corr GEMM: 256x256 tile, 8 waves, dbuf, 1 barrier/K-tile --
// K-tile = (q, m): 16 channels x 3 comps. Wave (wr,wc) owns 128r x 64l =
// 4x2 frags of 32x32. Issue-after-barrier => full-tile prefetch distance,
// so the __syncthreads vmcnt drain waits on ~3700-cycle-old loads (free).
__global__ __launch_bounds__(512, 2)
void k_corrmax(float* __restrict__ ws) {
    __shared__ __align__(16) char LDSB[2 * BUFB];   // 112 KB double buffer

    int tid  = threadIdx.x;
    int b    = blockIdx.z;
    int bx   = blockIdx.x;
    int by   = blockIdx.y;
    int l0   = bx * 256;
    int rbs  = by * RPS;

    int lane = tid & 63;
    int w    = __builtin_amdgcn_readfirstlane(tid >> 6);   // scalar wave id
    int wr   = w >> 2;          // r half 0..1 (128 rows)
    int wc   = w & 3;           // l quarter 0..3 (64 cols)
    int l31  = lane & 31;
    int g2   = lane >> 5;       // k-octet selector

    const float* invn_rs = ws + WS_INV_RS + b * LL;
    const char*  gpB = (const char*)ws + GP_BYTE_BASE + b * GP_B_STRIDE;

    // ---- staging constants: 7 granules per thread (3584 = 512*7) ----
    // granule G = n*512 + tid; side split at 1792 (wave-uniform: 8n+w>=28)
    int LC[7];
    int sideF[7];
    #pragma unroll
    for (int n = 0; n < 7; ++n) {
        int G    = n * 512 + tid;
        int side = (n * 8 + w >= 28) ? 1 : 0;
        int gg   = G - side * 1792;
        int row  = gg / 7;
        int slot = gg - row * 7;
        int comp = (slot >= 6) ? 0 : (slot >> 1);
        int oct  = (slot >= 6) ? 0 : (slot & 1);
        LC[n] = side * GP_SIDE_STRIDE + comp * GP_COMP_STRIDE + oct * (PAD_L * 16)
              + (row + 2 * (row >> 6)) * 16;
        sideF[n] = side;
    }

    // ---- fragment LDS byte bases (mf adds +32*RSTB, comp c adds +c*32) ----
    int abase = (wr * 128 + l31) * RSTB + g2 * 16;
    int bbase = BSOFF + (wc * 64 + l31) * RSTB + g2 * 16;

    int ybA = by * 16;          // A-side y base (rbs>>6)
    int ybB = bx * 4;           // B-side y base

    auto issue = [&](int rt2, int q2, int m2, int bufo) {
        int i2 = (q2 < 3) ? -1 : ((q2 < 6) ? 0 : 1);
        int j2 = q2 - (i2 + 1) * 3 - 1;
        int suA = ((ybA + rt2 * 4 + 1 + i2) * 66 + 1 + j2) * 16 + m2 * CSTRIDE;
        int suB = ((ybB + 1 + i2) * 66 + 1 + j2) * 16 + m2 * CSTRIDE;
        #pragma unroll
        for (int n = 0; n < 7; ++n) {
            int su = sideF[n] ? suB : suA;   // wave-uniform select
            gload16(gpB + (LC[n] + su), LDSB + bufo + n * 8192 + tid * 16);
        }
    };

    float rm[2] = {-1e30f, -1e30f};   // running max per nf column
    int   ra[2] = {0, 0};

    issue(0, 0, 0, 0);
    int cur = 0;

    for (int rt = 0; rt < NRT; ++rt) {
        int r0 = rbs + rt * 256;

        f32x16 acc[4][2];
        #pragma unroll
        for (int mf = 0; mf < 4; ++mf)
            #pragma unroll
            for (int nf = 0; nf < 2; ++nf)
                #pragma unroll
                for (int e = 0; e < 16; ++e) acc[mf][nf][e] = 0.f;

        for (int q = 0; q < 9; ++q) {
            for (int m = 0; m < 4; ++m) {
                __syncthreads();   // vmcnt(0)+lgkmcnt(0)+barrier: tile ready,
                                   // all waves done with the other buffer
                // ---- issue next K-tile into the other buffer ----
                {
                    int m2 = m + 1, q2 = q, rt2 = rt;
                    if (m2 == 4) { m2 = 0; ++q2; if (q2 == 9) { q2 = 0; ++rt2; } }
                    if (rt2 < NRT) issue(rt2, q2, m2, (cur ^ 1) * BUFB);
                }
                // ---- fragments + 6-product MFMA from current buffer ----
                const char* lb = LDSB + cur * BUFB;
                short8b bfr[2][3];
                #pragma unroll
                for (int nf = 0; nf < 2; ++nf)
                    #pragma unroll
                    for (int c = 0; c < 3; ++c)
                        bfr[nf][c] = *(const short8b*)(lb + bbase + nf * (32 * RSTB) + c * 32);
                #pragma unroll
                for (int mfh = 0; mfh < 2; ++mfh) {
                    short8b afr[2][3];
                    #pragma unroll
                    for (int mi = 0; mi < 2; ++mi)
                        #pragma unroll
                        for (int c = 0; c < 3; ++c)
                            afr[mi][c] = *(const short8b*)(lb + abase + (mfh * 2 + mi) * (32 * RSTB) + c * 32);
                    __builtin_amdgcn_s_setprio(1);
                    #pragma unroll
                    for (int mi = 0; mi < 2; ++mi)
                        #pragma unroll
                        for (int nf = 0; nf < 2; ++nf) {
                            f32x16 d = acc[mfh * 2 + mi][nf];
                            d = __builtin_amdgcn_mfma_f32_32x32x16_bf16(afr[mi][0], bfr[nf][0], d, 0, 0, 0);
                            d = __builtin_amdgcn_mfma_f32_32x32x16_bf16(afr[mi][0], bfr[nf][1], d, 0, 0, 0);
                            d = __builtin_amdgcn_mfma_f32_32x32x16_bf16(afr[mi][1], bfr[nf][0], d, 0, 0, 0);
                            d = __builtin_amdgcn_mfma_f32_32x32x16_bf16(afr[mi][1], bfr[nf][1], d, 0, 0, 0);
                            d = __builtin_amdgcn_mfma_f32_32x32x16_bf16(afr[mi][0], bfr[nf][2], d, 0, 0, 0);
                            d = __builtin_amdgcn_mfma_f32_32x32x16_bf16(afr[mi][2], bfr[nf][0], d, 0, 0, 0);
                            acc[mfh * 2 + mi][nf] = d;
                        }
                    __builtin_amdgcn_s_setprio(0);
                }
                cur ^= 1;
            }
        }

        // ---- epilogue (registers only; pipeline continues across it) ----
        // C layout: col = lane&31, row = (reg&3) + 8*(reg>>2) + 4*(lane>>5)
        #pragma unroll
        for (int mf = 0; mf < 4; ++mf) {
            f32x4 iv[4];
            #pragma unroll
            for (int rb = 0; rb < 4; ++rb)
                iv[rb] = *(const f32x4*)&invn_rs[r0 + wr * 128 + mf * 32 + g2 * 4 + rb * 8];
            #pragma unroll
            for (int nf = 0; nf < 2; ++nf)
                #pragma unroll
                for (int reg = 0; reg < 16; ++reg) {
                    int r = r0 + wr * 128 + mf * 32 + (reg & 3) + 8 * (reg >> 2) + 4 * g2;
                    float val = acc[mf][nf][reg] * iv[reg >> 2][reg & 3];
                    if (val > rm[nf] || (val == rm[nf] && r < ra[nf])) { rm[nf] = val; ra[nf] = r; }
                }
        }
    }

    // ---- lane-pair merge (lanes l, l+32 hold same column) ----
    #pragma unroll
    for (int nf = 0; nf < 2; ++nf) {
        float ov = __shfl_xor(rm[nf], 32);
        int   oi = __shfl_xor(ra[nf], 32);
        if (ov > rm[nf] || (ov == rm[nf] && oi < ra[nf])) { rm[nf] = ov; ra[nf] = oi; }
    }
    // ---- cross-wave merge (DMA fully drained: nothing issued after last tile) ----
    __syncthreads();
    float* sm2 = (float*)LDSB;          // [2][256]
    int*   si2 = (int*)LDSB + 512;      // [2][256]
    if (lane < 32) {
        #pragma unroll
        for (int nf = 0; nf < 2; ++nf) {
            sm2[wr * 256 + wc * 64 + nf * 32 + l31] = rm[nf];
            si2[wr * 256 + wc * 64 + nf * 32 + l31] = ra[nf];
        }
    }
    __syncthreads();
    if (tid < 256) {
        float bm = sm2[tid]; int ba = si2[tid];
        float v  = sm2[256 + tid]; int a2 = si2[256 + tid];
        if (v > bm || (v == bm && a2 < ba)) { bm = v; ba = a2; }
        int l = l0 + tid;
        int o = (b * SPLITS + by) * LL + l;
        ws[WS_PMAX + o] = bm;
        ((int*)ws)[WS_PARG + o] = ba;
    }
}

// -------- 4) reduce over splits -> s output + final argmax --------
__global__ void k_reduce(float* __restrict__ ws, float* __restrict__ out) {
    int t = blockIdx.x * 256 + threadIdx.x;   // 0..B*L-1
    int b = t >> 12;
    int l = t & (LL - 1);
    float bm = -1e30f; int ba = 0;
    for (int s = 0; s < SPLITS; ++s) {        // splits are ascending r ranges
        int o = (b * SPLITS + s) * LL + l;
        float v = ws[WS_PMAX + o];
        int   a = ((int*)ws)[WS_PARG + o];
        if (v > bm || (v == bm && a < ba)) { bm = v; ba = a; }
    }
    out[t] = bm * ws[WS_INV_LR + t];          // s: [B,1,H,W] flat
    ((int*)ws)[WS_ARG + t] = ba;
}

// -------- 5) gather from ref via argmax + fold(3x3, pad 1) --------
__global__ void k_fold(const float* __restrict__ ref,
                       const float* __restrict__ ws,
                       float* __restrict__ out) {
    int t = blockIdx.x * 256 + threadIdx.x;   // 0..B*C*L-1
    int b = t >> 18;
    int c = (t >> 12) & 63;
    int yx = t & (LL - 1);
    int y = yx >> 6, x = yx & 63;
    const int* ab = ((const int*)ws) + WS_ARG + b * LL;
    const float* rb = ref + (size_t)b * CH * LL + c * LL;
    float s = 0.f;
    #pragma unroll
    for (int i = 0; i < 3; ++i) {
        int yp = y + 1 - i;
        if ((unsigned)yp >= (unsigned)HH) continue;
        #pragma unroll
        for (int j = 0; j < 3; ++j) {
            int xp = x + 1 - j;
            if ((unsigned)xp >= (unsigned)WW) continue;
            int r = ab[yp * WW + xp];
            int ry = (r >> 6) + i - 1;
            int rx = (r & 63) + j - 1;
            if ((unsigned)ry < (unsigned)HH && (unsigned)rx < (unsigned)WW)
                s += rb[ry * WW + rx];
        }
    }
    out[BATCH * LL + t] = s;                  // trans after s (16384 floats)
}

extern "C" void kernel_launch(void* const* d_in, const int* in_sizes, int n_in,
                              void* d_out, int out_size, void* d_ws, size_t ws_size,
                              hipStream_t stream) {
    const float* lrsr = (const float*)d_in[0];
    const float* refsr = (const float*)d_in[1];
    const float* ref  = (const float*)d_in[2];
    float* out = (float*)d_out;
    float* ws  = (float*)d_ws;

    // zero the padded pre-split region (borders must be 0)
    hipMemsetAsync((char*)d_ws + GP_BYTE_BASE, 0, GP_TOTAL, stream);
    k_split<<<dim3(16, 8, 8), dim3(256), 0, stream>>>(lrsr, refsr, ws);
    k_ssq<<<dim3(BATCH * LL / 256), dim3(256), 0, stream>>>(lrsr, refsr, ws);
    k_inv<<<dim3(BATCH * LL / 256), dim3(256), 0, stream>>>(ws);
    k_corrmax<<<dim3(16, SPLITS, BATCH), dim3(512), 0, stream>>>(ws);
    k_reduce<<<dim3(BATCH * LL / 256), dim3(256), 0, stream>>>(ws, out);
    k_fold<<<dim3(BATCH * CH * LL / 256), dim3(256), 0, stream>>>(ref, ws, out);
}

// Round 11
// 400.900 us; speedup vs baseline: 1.4036x; 1.0090x over previous
//
#include <hip/hip_runtime.h>

// Problem constants
#define BATCH 4
#define CH    64
#define HH    64
#define WW    64
#define LL    4096          // HH*WW
#define SPLITS 4
#define RPS   1024          // LL/SPLITS
#define NRT   4             // r-tiles of 256 per block

// LDS K-tile buffer: per side 256 rows x 112 B (7 granules: 6 data + 1 dummy)
#define RSTB  112
#define BUFB  57344         // bytes per stage buffer (A 28KB | B 28KB)
#define BSOFF 28672         // B side byte offset within buffer
#define CSTRIDE 139392      // 16-ch group stride: 2*PAD_L*16

// Padded pre-split global image Gp[side][b][comp][c8(8)][4356][8ch] (ushort)
#define PAD_L   4356        // 66*66
#define GP_BYTE_BASE 1048576
#define GP_SIDE_STRIDE 6690816   // 4*3*8*4356*8*2
#define GP_B_STRIDE    1672704   // 3*8*4356*8*2
#define GP_COMP_STRIDE 557568    // 8*4356*16
#define GP_TOTAL       13381632  // 2*GP_SIDE_STRIDE

// Workspace layout (float words)
#define WS_SSQ_RS 0
#define WS_SSQ_LR 16384
#define WS_INV_RS 32768
#define WS_INV_LR 49152
#define WS_PMAX   65536      // [B*SPLITS*L] = 65536
#define WS_PARG   131072     // [B*SPLITS*L] = 65536
#define WS_ARG    196608     // [B*L]

typedef __attribute__((ext_vector_type(8))) short short8b;
typedef __attribute__((ext_vector_type(4))) float f32x4;
typedef __attribute__((ext_vector_type(16))) float f32x16;

__device__ __forceinline__ void gload16(const void* g, void* l) {
    __builtin_amdgcn_global_load_lds(
        (const __attribute__((address_space(1))) unsigned int*)g,
        (__attribute__((address_space(3))) unsigned int*)l, 16, 0, 0);
}

// -------- 0) pre-split: fp32 -> 3 truncated bf16 comps, padded image --------
__global__ void k_split(const float* __restrict__ lrsr,
                        const float* __restrict__ refsr,
                        float* __restrict__ ws) {
    int tid  = threadIdx.x;
    int pos  = blockIdx.x * 256 + tid;          // 0..4095
    int c8   = blockIdx.y;                      // 0..7
    int side = blockIdx.z >> 2;                 // 0 = refsr(A), 1 = lrsr(B)
    int b    = blockIdx.z & 3;
    const float* src = (side ? lrsr : refsr) + (size_t)b * CH * LL + c8 * 8 * LL + pos;
    int ppos = (pos >> 6) * 66 + (pos & 63) + 67;   // (y+1)*66 + (x+1)
    char* dst = (char*)ws + GP_BYTE_BASE + side * GP_SIDE_STRIDE + b * GP_B_STRIDE
              + (size_t)(c8 * PAD_L + ppos) * 16;
    union { unsigned short u[8]; uint4 v; } w0, w1, w2;
    #pragma unroll
    for (int cc = 0; cc < 8; ++cc) {
        float x = src[cc * LL];
        unsigned u0 = __float_as_uint(x);
        float f0 = __uint_as_float(u0 & 0xffff0000u);
        float r1 = x - f0;
        unsigned u1 = __float_as_uint(r1);
        float f1 = __uint_as_float(u1 & 0xffff0000u);
        float r2 = r1 - f1;
        w0.u[cc] = (unsigned short)(u0 >> 16);
        w1.u[cc] = (unsigned short)(u1 >> 16);
        w2.u[cc] = (unsigned short)(__float_as_uint(r2) >> 16);
    }
    *(uint4*)(dst)                      = w0.v;
    *(uint4*)(dst + GP_COMP_STRIDE)     = w1.v;
    *(uint4*)(dst + 2 * GP_COMP_STRIDE) = w2.v;
}

// -------- 1) channel sum-of-squares per position (both inputs) --------
__global__ void k_ssq(const float* __restrict__ lrsr,
                      const float* __restrict__ refsr,
                      float* __restrict__ ws) {
    int t = blockIdx.x * 256 + threadIdx.x;      // 0..B*L-1
    int b = t >> 12;
    int r = t & (LL - 1);
    const float* pl = lrsr + (size_t)b * CH * LL + r;
    const float* pr = refsr + (size_t)b * CH * LL + r;
    float sl = 0.f, sr = 0.f;
    #pragma unroll 8
    for (int c = 0; c < CH; ++c) {
        float a = pl[c * LL]; sl += a * a;
        float d = pr[c * LL]; sr += d * d;
    }
    ws[WS_SSQ_RS + t] = sr;
    ws[WS_SSQ_LR + t] = sl;
}

// -------- 2) 3x3 box-sum of ssq (zero pad) -> 1/max(norm,eps) --------
__global__ void k_inv(float* __restrict__ ws) {
    int t = blockIdx.x * 256 + threadIdx.x;      // 0..B*L-1
    int b = t >> 12;
    int r = t & (LL - 1);
    int y = r >> 6, x = r & 63;
    float srs = 0.f, slr = 0.f;
    for (int di = -1; di <= 1; ++di) {
        int yy = y + di;
        if ((unsigned)yy >= (unsigned)HH) continue;
        for (int dj = -1; dj <= 1; ++dj) {
            int xx = x + dj;
            if ((unsigned)xx >= (unsigned)WW) continue;
            int idx = b * LL + yy * WW + xx;
            srs += ws[WS_SSQ_RS + idx];
            slr += ws[WS_SSQ_LR + idx];
        }
    }
    ws[WS_INV_RS + t] = 1.f / fmaxf(sqrtf(srs), 1e-12f);
    ws[WS_INV_LR + t] = 1.f / fmaxf(sqrtf(slr), 1e-12f);
}

// -------- 3) MFMA corr GEMM: 256x256 tile, 8 waves, dbuf, 1 barrier/K-tile --
// XCD-aware decode: linear L -> xcd = L&7 = 2*b + (by>>1). Each XCD then
// serves ONE batch with A-half (0.84 MB) + full B (1.67 MB) = 2.5 MB < 4 MB
// L2 -> fetch path becomes L2-resident, the per-tile vmcnt drain goes free.
__global__ __launch_bounds__(512, 2)
void k_corrmax(float* __restrict__ ws) {
    __shared__ __align__(16) char LDSB[2 * BUFB];   // 112 KB double buffer

    int tid  = threadIdx.x;
    int L    = blockIdx.x;                 // 0..255
    int xcd  = L & 7;
    int slot = L >> 3;
    int b    = xcd >> 1;
    int bx   = slot >> 1;                  // 0..15
    int by   = ((xcd & 1) << 1) | (slot & 1);   // 0..3
    int l0   = bx * 256;
    int rbs  = by * RPS;

    int lane = tid & 63;
    int w    = __builtin_amdgcn_readfirstlane(tid >> 6);   // scalar wave id
    int wr   = w >> 2;          // r half 0..1 (128 rows)
    int wc   = w & 3;           // l quarter 0..3 (64 cols)
    int l31  = lane & 31;
    int g2   = lane >> 5;       // k-octet selector

    const float* invn_rs = ws + WS_INV_RS + b * LL;
    const char*  gpB = (const char*)ws + GP_BYTE_BASE + b * GP_B_STRIDE;

    // ---- staging constants: 7 granules per thread (3584 = 512*7) ----
    // granule G = n*512 + tid; side split at 1792 (wave-uniform: 8n+w>=28)
    int LC[7];
    int sideF[7];
    #pragma unroll
    for (int n = 0; n < 7; ++n) {
        int G    = n * 512 + tid;
        int side = (n * 8 + w >= 28) ? 1 : 0;
        int gg   = G - side * 1792;
        int row  = gg / 7;
        int slot2 = gg - row * 7;
        int comp = (slot2 >= 6) ? 0 : (slot2 >> 1);
        int oct  = (slot2 >= 6) ? 0 : (slot2 & 1);
        LC[n] = side * GP_SIDE_STRIDE + comp * GP_COMP_STRIDE + oct * (PAD_L * 16)
              + (row + 2 * (row >> 6)) * 16;
        sideF[n] = side;
    }

    // ---- fragment LDS byte bases (mf adds +32*RSTB, comp c adds +c*32) ----
    int abase = (wr * 128 + l31) * RSTB + g2 * 16;
    int bbase = BSOFF + (wc * 64 + l31) * RSTB + g2 * 16;

    int ybA = by * 16;          // A-side y base (rbs>>6)
    int ybB = bx * 4;           // B-side y base

    auto issue = [&](int rt2, int q2, int m2, int bufo) {
        int i2 = (q2 < 3) ? -1 : ((q2 < 6) ? 0 : 1);
        int j2 = q2 - (i2 + 1) * 3 - 1;
        int suA = ((ybA + rt2 * 4 + 1 + i2) * 66 + 1 + j2) * 16 + m2 * CSTRIDE;
        int suB = ((ybB + 1 + i2) * 66 + 1 + j2) * 16 + m2 * CSTRIDE;
        #pragma unroll
        for (int n = 0; n < 7; ++n) {
            int su = sideF[n] ? suB : suA;   // wave-uniform select
            gload16(gpB + (LC[n] + su), LDSB + bufo + n * 8192 + tid * 16);
        }
    };

    float rm[2] = {-1e30f, -1e30f};   // running max per nf column
    int   ra[2] = {0, 0};

    issue(0, 0, 0, 0);
    int cur = 0;

    for (int rt = 0; rt < NRT; ++rt) {
        int r0 = rbs + rt * 256;

        f32x16 acc[4][2];
        #pragma unroll
        for (int mf = 0; mf < 4; ++mf)
            #pragma unroll
            for (int nf = 0; nf < 2; ++nf)
                #pragma unroll
                for (int e = 0; e < 16; ++e) acc[mf][nf][e] = 0.f;

        for (int q = 0; q < 9; ++q) {
            for (int m = 0; m < 4; ++m) {
                __syncthreads();   // vmcnt(0)+lgkmcnt(0)+barrier: tile ready,
                                   // all waves done with the other buffer
                // ---- issue next K-tile into the other buffer ----
                {
                    int m2 = m + 1, q2 = q, rt2 = rt;
                    if (m2 == 4) { m2 = 0; ++q2; if (q2 == 9) { q2 = 0; ++rt2; } }
                    if (rt2 < NRT) issue(rt2, q2, m2, (cur ^ 1) * BUFB);
                }
                // ---- fragments + 6-product MFMA from current buffer ----
                const char* lb = LDSB + cur * BUFB;
                short8b bfr[2][3];
                #pragma unroll
                for (int nf = 0; nf < 2; ++nf)
                    #pragma unroll
                    for (int c = 0; c < 3; ++c)
                        bfr[nf][c] = *(const short8b*)(lb + bbase + nf * (32 * RSTB) + c * 32);
                #pragma unroll
                for (int mfh = 0; mfh < 2; ++mfh) {
                    short8b afr[2][3];
                    #pragma unroll
                    for (int mi = 0; mi < 2; ++mi)
                        #pragma unroll
                        for (int c = 0; c < 3; ++c)
                            afr[mi][c] = *(const short8b*)(lb + abase + (mfh * 2 + mi) * (32 * RSTB) + c * 32);
                    __builtin_amdgcn_s_setprio(1);
                    #pragma unroll
                    for (int mi = 0; mi < 2; ++mi)
                        #pragma unroll
                        for (int nf = 0; nf < 2; ++nf) {
                            f32x16 d = acc[mfh * 2 + mi][nf];
                            d = __builtin_amdgcn_mfma_f32_32x32x16_bf16(afr[mi][0], bfr[nf][0], d, 0, 0, 0);
                            d = __builtin_amdgcn_mfma_f32_32x32x16_bf16(afr[mi][0], bfr[nf][1], d, 0, 0, 0);
                            d = __builtin_amdgcn_mfma_f32_32x32x16_bf16(afr[mi][1], bfr[nf][0], d, 0, 0, 0);
                            d = __builtin_amdgcn_mfma_f32_32x32x16_bf16(afr[mi][1], bfr[nf][1], d, 0, 0, 0);
                            d = __builtin_amdgcn_mfma_f32_32x32x16_bf16(afr[mi][0], bfr[nf][2], d, 0, 0, 0);
                            d = __builtin_amdgcn_mfma_f32_32x32x16_bf16(afr[mi][2], bfr[nf][0], d, 0, 0, 0);
                            acc[mfh * 2 + mi][nf] = d;
                        }
                    __builtin_amdgcn_s_setprio(0);
                }
                cur ^= 1;
            }
        }

        // ---- epilogue (registers only; pipeline continues across it) ----
        // C layout: col = lane&31, row = (reg&3) + 8*(reg>>2) + 4*(lane>>5)
        #pragma unroll
        for (int mf = 0; mf < 4; ++mf) {
            f32x4 iv[4];
            #pragma unroll
            for (int rb = 0; rb < 4; ++rb)
                iv[rb] = *(const f32x4*)&invn_rs[r0 + wr * 128 + mf * 32 + g2 * 4 + rb * 8];
            #pragma unroll
            for (int nf = 0; nf < 2; ++nf)
                #pragma unroll
                for (int reg = 0; reg < 16; ++reg) {
                    int r = r0 + wr * 128 + mf * 32 + (reg & 3) + 8 * (reg >> 2) + 4 * g2;
                    float val = acc[mf][nf][reg] * iv[reg >> 2][reg & 3];
                    if (val > rm[nf] || (val == rm[nf] && r < ra[nf])) { rm[nf] = val; ra[nf] = r; }
                }
        }
    }

    // ---- lane-pair merge (lanes l, l+32 hold same column) ----
    #pragma unroll
    for (int nf = 0; nf < 2; ++nf) {
        float ov = __shfl_xor(rm[nf], 32);
        int   oi = __shfl_xor(ra[nf], 32);
        if (ov > rm[nf] || (ov == rm[nf] && oi < ra[nf])) { rm[nf] = ov; ra[nf] = oi; }
    }
    // ---- cross-wave merge (DMA fully drained: nothing issued after last tile) ----
    __syncthreads();
    float* sm2 = (float*)LDSB;          // [2][256]
    int*   si2 = (int*)LDSB + 512;      // [2][256]
    if (lane < 32) {
        #pragma unroll
        for (int nf = 0; nf < 2; ++nf) {
            sm2[wr * 256 + wc * 64 + nf * 32 + l31] = rm[nf];
            si2[wr * 256 + wc * 64 + nf * 32 + l31] = ra[nf];
        }
    }
    __syncthreads();
    if (tid < 256) {
        float bm = sm2[tid]; int ba = si2[tid];
        float v  = sm2[256 + tid]; int a2 = si2[256 + tid];
        if (v > bm || (v == bm && a2 < ba)) { bm = v; ba = a2; }
        int l = l0 + tid;
        int o = (b * SPLITS + by) * LL + l;
        ws[WS_PMAX + o] = bm;
        ((int*)ws)[WS_PARG + o] = ba;
    }
}

// -------- 4) reduce over splits -> s output + final argmax --------
__global__ void k_reduce(float* __restrict__ ws, float* __restrict__ out) {
    int t = blockIdx.x * 256 + threadIdx.x;   // 0..B*L-1
    int b = t >> 12;
    int l = t & (LL - 1);
    float bm = -1e30f; int ba = 0;
    for (int s = 0; s < SPLITS; ++s) {        // splits are ascending r ranges
        int o = (b * SPLITS + s) * LL + l;
        float v = ws[WS_PMAX + o];
        int   a = ((int*)ws)[WS_PARG + o];
        if (v > bm || (v == bm && a < ba)) { bm = v; ba = a; }
    }
    out[t] = bm * ws[WS_INV_LR + t];          // s: [B,1,H,W] flat
    ((int*)ws)[WS_ARG + t] = ba;
}

// -------- 5) gather from ref via argmax + fold(3x3, pad 1) --------
__global__ void k_fold(const float* __restrict__ ref,
                       const float* __restrict__ ws,
                       float* __restrict__ out) {
    int t = blockIdx.x * 256 + threadIdx.x;   // 0..B*C*L-1
    int b = t >> 18;
    int c = (t >> 12) & 63;
    int yx = t & (LL - 1);
    int y = yx >> 6, x = yx & 63;
    const int* ab = ((const int*)ws) + WS_ARG + b * LL;
    const float* rb = ref + (size_t)b * CH * LL + c * LL;
    float s = 0.f;
    #pragma unroll
    for (int i = 0; i < 3; ++i) {
        int yp = y + 1 - i;
        if ((unsigned)yp >= (unsigned)HH) continue;
        #pragma unroll
        for (int j = 0; j < 3; ++j) {
            int xp = x + 1 - j;
            if ((unsigned)xp >= (unsigned)WW) continue;
            int r = ab[yp * WW + xp];
            int ry = (r >> 6) + i - 1;
            int rx = (r & 63) + j - 1;
            if ((unsigned)ry < (unsigned)HH && (unsigned)rx < (unsigned)WW)
                s += rb[ry * WW + rx];
        }
    }
    out[BATCH * LL + t] = s;                  // trans after s (16384 floats)
}

extern "C" void kernel_launch(void* const* d_in, const int* in_sizes, int n_in,
                              void* d_out, int out_size, void* d_ws, size_t ws_size,
                              hipStream_t stream) {
    const float* lrsr = (const float*)d_in[0];
    const float* refsr = (const float*)d_in[1];
    const float* ref  = (const float*)d_in[2];
    float* out = (float*)d_out;
    float* ws  = (float*)d_ws;

    // zero the padded pre-split region (borders must be 0)
    hipMemsetAsync((char*)d_ws + GP_BYTE_BASE, 0, GP_TOTAL, stream);
    k_split<<<dim3(16, 8, 8), dim3(256), 0, stream>>>(lrsr, refsr, ws);
    k_ssq<<<dim3(BATCH * LL / 256), dim3(256), 0, stream>>>(lrsr, refsr, ws);
    k_inv<<<dim3(BATCH * LL / 256), dim3(256), 0, stream>>>(ws);
    k_corrmax<<<dim3(256), dim3(512), 0, stream>>>(ws);
    k_reduce<<<dim3(BATCH * LL / 256), dim3(256), 0, stream>>>(ws, out);
    k_fold<<<dim3(BATCH * CH * LL / 256), dim3(256), 0, stream>>>(ref, ws, out);
}